// Round 3
// baseline (407.341 us; speedup 1.0000x reference)
//
#include <hip/hip_runtime.h>

// Problem constants: B=8, N=2048, C=512, CR=64
typedef __attribute__((ext_vector_type(4))) float f32x4;
typedef __attribute__((ext_vector_type(8))) __bf16 bf16x8;
typedef __attribute__((ext_vector_type(8))) unsigned short u16x8;

__device__ __forceinline__ unsigned short f2bf(float f) {
  unsigned u = __builtin_bit_cast(unsigned, f);
  u += 0x7fffu + ((u >> 16) & 1u);
  return (unsigned short)(u >> 16);
}
__device__ __forceinline__ unsigned pack2bf(float lo, float hi) {
  return (unsigned)f2bf(lo) | ((unsigned)f2bf(hi) << 16);
}
__device__ __forceinline__ u16x8 cvt8(float4 a, float4 b) {
  u16x8 h;
  h[0] = f2bf(a.x); h[1] = f2bf(a.y); h[2] = f2bf(a.z); h[3] = f2bf(a.w);
  h[4] = f2bf(b.x); h[5] = f2bf(b.y); h[6] = f2bf(b.z); h[7] = f2bf(b.w);
  return h;
}
__device__ __forceinline__ bf16x8 frag_at(const unsigned short* p) {
  return *reinterpret_cast<const bf16x8*>(p);
}
__device__ __forceinline__ f32x4 mfma16(bf16x8 a, bf16x8 b, f32x4 c) {
  return __builtin_amdgcn_mfma_f32_16x16x32_bf16(a, b, c, 0, 0, 0);
}

// ---------------- prep: cast weights to bf16, concat Wk/Wv ----------------
__global__ void prep_kernel(const float* __restrict__ Wk, const float* __restrict__ bk,
                            const float* __restrict__ Wv, const float* __restrict__ bv,
                            const float* __restrict__ Wq,
                            unsigned short* __restrict__ W1, float* __restrict__ b1,
                            unsigned short* __restrict__ Wqb) {
  int i = blockIdx.x * blockDim.x + threadIdx.x;
  int stride = gridDim.x * blockDim.x;
  for (int t = i; t < 128 * 512; t += stride) {
    int o = t >> 9, c = t & 511;
    float v = (o < 64) ? Wk[o * 512 + c] : Wv[(o - 64) * 512 + c];
    W1[t] = f2bf(v);
  }
  for (int t = i; t < 512 * 512; t += stride) Wqb[t] = f2bf(Wq[t]);
  if (i < 64) b1[i] = bk[i];
  else if (i < 128) b1[i] = bv[i - 64];
}

// ---------------- P1: k[b,n,64], vt[b,n,64] = x @ [Wk;Wv]^T + bias --------
// M=16384 tokens, N'=128, K=512, BK=64 (8 iters, 16 barriers total)
__global__ __launch_bounds__(256) void proj_kv_kernel(
    const float* __restrict__ x, const unsigned short* __restrict__ W1,
    const float* __restrict__ b1,
    unsigned short* __restrict__ kbf, unsigned short* __restrict__ vtbf) {
  __shared__ unsigned short As[64][72];    // [token][k]
  __shared__ unsigned short Bs[128][72];   // [o][k]
  const int t = threadIdx.x;
  const int m0 = blockIdx.x * 64;
  const int w = t >> 6, lane = t & 63, lr = lane & 15, lg = lane >> 4;
  f32x4 acc[8];
#pragma unroll
  for (int i = 0; i < 8; ++i) acc[i] = (f32x4){0.f, 0.f, 0.f, 0.f};

  for (int kk = 0; kk < 8; ++kk) {
    const int k0 = kk * 64;
    {  // stage A: 64 x 64 fp32 -> bf16 (16 elems/thread)
      int row = t >> 2, q = t & 3;
      const float4* src = reinterpret_cast<const float4*>(
          x + (size_t)(m0 + row) * 512 + k0 + q * 16);
      float4 f0 = src[0], f1 = src[1], f2 = src[2], f3 = src[3];
      *reinterpret_cast<u16x8*>(&As[row][q * 16])     = cvt8(f0, f1);
      *reinterpret_cast<u16x8*>(&As[row][q * 16 + 8]) = cvt8(f2, f3);
    }
    {  // stage B: 128 x 64 bf16 (32 elems/thread)
      int row = t >> 1, h = t & 1;
      const uint4* src = reinterpret_cast<const uint4*>(
          W1 + (size_t)row * 512 + k0 + h * 32);
      uint4 d0 = src[0], d1 = src[1], d2 = src[2], d3 = src[3];
      *reinterpret_cast<uint4*>(&Bs[row][h * 32])      = d0;
      *reinterpret_cast<uint4*>(&Bs[row][h * 32 + 8])  = d1;
      *reinterpret_cast<uint4*>(&Bs[row][h * 32 + 16]) = d2;
      *reinterpret_cast<uint4*>(&Bs[row][h * 32 + 24]) = d3;
    }
    __syncthreads();
#pragma unroll
    for (int s = 0; s < 2; ++s) {
      bf16x8 af = frag_at(&As[w * 16 + lr][s * 32 + lg * 8]);
#pragma unroll
      for (int cb = 0; cb < 8; ++cb) {
        bf16x8 bfr = frag_at(&Bs[cb * 16 + lr][s * 32 + lg * 8]);
        acc[cb] = mfma16(af, bfr, acc[cb]);
      }
    }
    __syncthreads();
  }
#pragma unroll
  for (int cb = 0; cb < 8; ++cb) {
    int o = cb * 16 + lr;
    float bias = b1[o];
#pragma unroll
    for (int i = 0; i < 4; ++i) {
      int token = m0 + w * 16 + lg * 4 + i;
      unsigned short hv = f2bf(acc[cb][i] + bias);
      if (o < 64) kbf[(size_t)token * 64 + o] = hv;
      else        vtbf[(size_t)token * 64 + (o - 64)] = hv;
    }
  }
}

// ---------------- P2: qt[b, c, n] = (Wq @ x[b]^T + bq) -------------------
// per b: M=512 (o), N=2048 (n), K=512. 128x128 tiles, BK=64, 512 thr.
__global__ __launch_bounds__(512) void proj_q_kernel(
    const float* __restrict__ x, const unsigned short* __restrict__ Wqb,
    const float* __restrict__ bq, unsigned short* __restrict__ qt) {
  __shared__ unsigned short As[128][72];   // [o][k]
  __shared__ unsigned short Bs[128][72];   // [n][k]
  const int t = threadIdx.x;
  const int bi = blockIdx.x;
  const int b = bi >> 6, rem = bi & 63, ot = rem >> 4, ntl = rem & 15;
  const int o0 = ot * 128, n0 = ntl * 128;
  const int w = t >> 6, lane = t & 63, lr = lane & 15, lg = lane >> 4;
  const int orr = w >> 2, nr = w & 3;   // wave: 64 o x 32 n sub-tile
  f32x4 acc[4][2];
#pragma unroll
  for (int a = 0; a < 4; ++a)
#pragma unroll
    for (int nb = 0; nb < 2; ++nb) acc[a][nb] = (f32x4){0.f, 0.f, 0.f, 0.f};

  for (int kk = 0; kk < 8; ++kk) {
    const int k0 = kk * 64;
    {  // stage A: Wq 128 x 64 bf16 (16/thread)
      int row = t >> 2, q = t & 3;
      const uint4* src = reinterpret_cast<const uint4*>(
          Wqb + (size_t)(o0 + row) * 512 + k0 + q * 16);
      uint4 d0 = src[0], d1 = src[1];
      *reinterpret_cast<uint4*>(&As[row][q * 16])     = d0;
      *reinterpret_cast<uint4*>(&As[row][q * 16 + 8]) = d1;
    }
    {  // stage B: x 128 x 64 fp32 -> bf16 (16/thread)
      int row = t >> 2, q = t & 3;
      const float4* src = reinterpret_cast<const float4*>(
          x + ((size_t)b * 2048 + n0 + row) * 512 + k0 + q * 16);
      float4 f0 = src[0], f1 = src[1], f2 = src[2], f3 = src[3];
      *reinterpret_cast<u16x8*>(&Bs[row][q * 16])     = cvt8(f0, f1);
      *reinterpret_cast<u16x8*>(&Bs[row][q * 16 + 8]) = cvt8(f2, f3);
    }
    __syncthreads();
#pragma unroll
    for (int s = 0; s < 2; ++s) {
      bf16x8 bfr[2];
#pragma unroll
      for (int nb = 0; nb < 2; ++nb)
        bfr[nb] = frag_at(&Bs[nr * 32 + nb * 16 + lr][s * 32 + lg * 8]);
#pragma unroll
      for (int ob = 0; ob < 4; ++ob) {
        bf16x8 af = frag_at(&As[orr * 64 + ob * 16 + lr][s * 32 + lg * 8]);
#pragma unroll
        for (int nb = 0; nb < 2; ++nb)
          acc[ob][nb] = mfma16(af, bfr[nb], acc[ob][nb]);
      }
    }
    __syncthreads();
  }
#pragma unroll
  for (int ob = 0; ob < 4; ++ob)
#pragma unroll
    for (int i = 0; i < 4; ++i) {
      int o = o0 + orr * 64 + ob * 16 + lg * 4 + i;
      float bias = bq[o];
#pragma unroll
      for (int nb = 0; nb < 2; ++nb) {
        int n = n0 + nr * 32 + nb * 16 + lr;
        qt[((size_t)b * 512 + o) * 2048 + n] = f2bf(acc[ob][nb][i] + bias);
      }
    }
}

// ---------------- attention: barrier-free ---------------------------------
// Block: (b = blockIdx&7 -> XCD-local, 64 m rows). 8 waves.
// Wave w: mq = w>>1 (16 m rows, S duplicated 2x), ch = w&1 (256-c half).
// S computed SWAPPED: sacc = mfma(K-rows as A, vt-rows as B) so lane 16g+m
// holds P[m][n=16nb+4g+i] -> denominator is lane-local; D->A-frag transpose
// is a wave-private LDS round trip (in-order DS + wave_barrier, NO
// __syncthreads anywhere in the loop).
__global__ __launch_bounds__(512) void attn_kernel(
    const float* __restrict__ x, const unsigned short* __restrict__ kbf,
    const unsigned short* __restrict__ vtbf, const unsigned short* __restrict__ qt,
    const float* __restrict__ g, float* __restrict__ out) {
  __shared__ unsigned int p_lds[8][16][36];  // per-wave [16 m][32+4pad words]
  const int t = threadIdx.x;
  const int b = blockIdx.x & 7, mt = blockIdx.x >> 3;
  const int m0 = mt * 64;
  const int w = t >> 6, lane = t & 63, lr = lane & 15, lg = lane >> 4;
  const int mq = w >> 1, ch = w & 1;

  // B-frags for S: vt rows of this wave's 16 m rows (K-dim = 64 c)
  const unsigned short* vrow = vtbf + (size_t)(b * 2048 + m0 + mq * 16 + lr) * 64;
  const bf16x8 qf0 = frag_at(vrow + lg * 8);
  const bf16x8 qf1 = frag_at(vrow + 32 + lg * 8);

  f32x4 acc[16];  // 16 m x 256 c per wave
#pragma unroll
  for (int i = 0; i < 16; ++i) acc[i] = (f32x4){0.f, 0.f, 0.f, 0.f};
  float dsum = 0.f;

  const unsigned short* kbase = kbf + (size_t)b * 2048 * 64;
  const unsigned short* qtb = qt + ((size_t)b * 512 + ch * 256) * 2048;
  unsigned int* pw = &p_lds[w][0][0];

  for (int nt = 0; nt < 32; ++nt) {
    const int n0 = nt * 64;

    // S (swapped): lane 16g+m gets P[m][n0+16nb+4g+i]
    f32x4 sacc[4];
#pragma unroll
    for (int nb = 0; nb < 4; ++nb) sacc[nb] = (f32x4){0.f, 0.f, 0.f, 0.f};
#pragma unroll
    for (int nb = 0; nb < 4; ++nb) {
      const unsigned short* krow = kbase + (size_t)(n0 + nb * 16 + lr) * 64;
      sacc[nb] = mfma16(frag_at(krow + lg * 8), qf0, sacc[nb]);
      sacc[nb] = mfma16(frag_at(krow + 32 + lg * 8), qf1, sacc[nb]);
    }

    // Pre-issue this tile's qt s=0 B-frags (independent of P) so their L2
    // latency hides under exp/pack/LDS.
    bf16x8 preA[16];
#pragma unroll
    for (int cb = 0; cb < 16; ++cb)
      preA[cb] = frag_at(qtb + (size_t)(cb * 16 + lr) * 2048 + n0 + lg * 8);

    // exp + lane-local denominator + pack + wave-private LDS write
#pragma unroll
    for (int nb = 0; nb < 4; ++nb) {
      float e0 = __expf(sacc[nb][0]);
      float e1 = __expf(sacc[nb][1]);
      float e2 = __expf(sacc[nb][2]);
      float e3 = __expf(sacc[nb][3]);
      dsum += (e0 + e1) + (e2 + e3);
      uint2 pk;
      pk.x = pack2bf(e0, e1);
      pk.y = pack2bf(e2, e3);
      *reinterpret_cast<uint2*>(&pw[lr * 36 + nb * 8 + lg * 2]) = pk;
    }
    __builtin_amdgcn_wave_barrier();  // order cross-lane LDS write -> read
    const bf16x8 pf0 = *reinterpret_cast<const bf16x8*>(&pw[lr * 36 + lg * 4]);
    const bf16x8 pf1 = *reinterpret_cast<const bf16x8*>(&pw[lr * 36 + 16 + lg * 4]);
    __builtin_amdgcn_wave_barrier();  // keep next iter's writes below reads

    // PV: acc[16m x 256c] += P . qt  (s=1 frags loaded inline; they hoist
    // above the pf0 MFMAs since they only depend on addresses)
#pragma unroll
    for (int cb = 0; cb < 16; ++cb)
      acc[cb] = mfma16(pf0, preA[cb], acc[cb]);
#pragma unroll
    for (int cb = 0; cb < 16; ++cb) {
      bf16x8 b1f = frag_at(qtb + (size_t)(cb * 16 + lr) * 2048 + n0 + 32 + lg * 8);
      acc[cb] = mfma16(pf1, b1f, acc[cb]);
    }
  }

  // Denominator: complete within wave. Combine the 4 lane groups per m.
  dsum += __shfl_xor(dsum, 16);
  dsum += __shfl_xor(dsum, 32);
  // Lane needs denom of rows m = 4*lg + i; that lives at lane 4*lg+i.
  float inv[4];
#pragma unroll
  for (int i = 0; i < 4; ++i) inv[i] = 1.0f / __shfl(dsum, lg * 4 + i);

  const float gamma = g[0];
#pragma unroll
  for (int cb = 0; cb < 16; ++cb) {
#pragma unroll
    for (int i = 0; i < 4; ++i) {
      const int m = m0 + mq * 16 + lg * 4 + i;
      const size_t idx = ((size_t)b * 2048 + m) * 512 + ch * 256 + cb * 16 + lr;
      out[idx] = gamma * acc[cb][i] * inv[i] + x[idx];
    }
  }
}

// ---------------- launcher ----------------
extern "C" void kernel_launch(void* const* d_in, const int* in_sizes, int n_in,
                              void* d_out, int out_size, void* d_ws, size_t ws_size,
                              hipStream_t stream) {
  const float* x  = (const float*)d_in[0];
  const float* Wk = (const float*)d_in[1];
  const float* bk = (const float*)d_in[2];
  const float* Wv = (const float*)d_in[3];
  const float* bv = (const float*)d_in[4];
  const float* Wq = (const float*)d_in[5];
  const float* bq = (const float*)d_in[6];
  const float* g  = (const float*)d_in[7];
  float* out = (float*)d_out;

  char* ws = (char*)d_ws;
  const size_t OFF_W1  = 0;                      // 128*512*2   = 131072
  const size_t OFF_WQ  = OFF_W1 + 131072;        // 512*512*2   = 524288
  const size_t OFF_B1  = OFF_WQ + 524288;        // 128*4       = 512
  const size_t OFF_K   = 656384;                 // 16384*64*2  = 2097152
  const size_t OFF_VT  = OFF_K + 2097152;
  const size_t OFF_QT  = OFF_VT + 2097152;       // 8*512*2048*2 = 16777216
  unsigned short* W1   = (unsigned short*)(ws + OFF_W1);
  unsigned short* Wqb  = (unsigned short*)(ws + OFF_WQ);
  float*          b1   = (float*)(ws + OFF_B1);
  unsigned short* kbf  = (unsigned short*)(ws + OFF_K);
  unsigned short* vtbf = (unsigned short*)(ws + OFF_VT);
  unsigned short* qt   = (unsigned short*)(ws + OFF_QT);

  hipLaunchKernelGGL(prep_kernel, dim3(256), dim3(256), 0, stream,
                     Wk, bk, Wv, bv, Wq, W1, b1, Wqb);
  hipLaunchKernelGGL(proj_kv_kernel, dim3(256), dim3(256), 0, stream,
                     x, W1, b1, kbf, vtbf);
  hipLaunchKernelGGL(proj_q_kernel, dim3(512), dim3(512), 0, stream,
                     x, Wqb, bq, qt);
  hipLaunchKernelGGL(attn_kernel, dim3(256), dim3(512), 0, stream,
                     x, kbf, vtbf, qt, g, out);
}

// Round 4
// 250.081 us; speedup vs baseline: 1.6288x; 1.6288x over previous
//
#include <hip/hip_runtime.h>

// Problem constants: B=8, N=2048, C=512, CR=64
typedef __attribute__((ext_vector_type(4))) float f32x4;
typedef __attribute__((ext_vector_type(8))) __bf16 bf16x8;
typedef __attribute__((ext_vector_type(8))) unsigned short u16x8;

__device__ __forceinline__ unsigned short f2bf(float f) {
  unsigned u = __builtin_bit_cast(unsigned, f);
  u += 0x7fffu + ((u >> 16) & 1u);
  return (unsigned short)(u >> 16);
}
__device__ __forceinline__ unsigned pack2bf(float lo, float hi) {
  return (unsigned)f2bf(lo) | ((unsigned)f2bf(hi) << 16);
}
__device__ __forceinline__ u16x8 cvt8(float4 a, float4 b) {
  u16x8 h;
  h[0] = f2bf(a.x); h[1] = f2bf(a.y); h[2] = f2bf(a.z); h[3] = f2bf(a.w);
  h[4] = f2bf(b.x); h[5] = f2bf(b.y); h[6] = f2bf(b.z); h[7] = f2bf(b.w);
  return h;
}
__device__ __forceinline__ bf16x8 frag_at(const unsigned short* p) {
  return *reinterpret_cast<const bf16x8*>(p);
}
__device__ __forceinline__ f32x4 mfma16(bf16x8 a, bf16x8 b, f32x4 c) {
  return __builtin_amdgcn_mfma_f32_16x16x32_bf16(a, b, c, 0, 0, 0);
}

// ---------------- fused projections ---------------------------------------
// blocks [0,128):   proj_kv: tile 128 tokens x 128 o (= all of [Wk;Wv])
// blocks [128,384): proj_q:  tile 256 o x 128 n per batch
// Weights staged fp32 -> bf16 on the fly (no prep kernel; weights are tiny
// and L2-resident after first touch).
__global__ __launch_bounds__(512, 2) void proj_all_kernel(
    const float* __restrict__ x,
    const float* __restrict__ Wk, const float* __restrict__ bk,
    const float* __restrict__ Wv, const float* __restrict__ bv,
    const float* __restrict__ Wq, const float* __restrict__ bq,
    unsigned short* __restrict__ kbf, unsigned short* __restrict__ vtbf,
    unsigned short* __restrict__ qt) {
  __shared__ unsigned short As[256][72];
  __shared__ unsigned short Bs[128][72];
  const int t = threadIdx.x;
  const int w = t >> 6, lane = t & 63, lr = lane & 15, lg = lane >> 4;

  if (blockIdx.x < 128) {
    // ---------------- proj_kv ----------------
    const int tok0 = blockIdx.x * 128;
    const int tr = w & 3, oh = w >> 2;  // wave: 32 tokens x 64 o
    f32x4 acc[2][4];
#pragma unroll
    for (int a = 0; a < 2; ++a)
#pragma unroll
      for (int c = 0; c < 4; ++c) acc[a][c] = (f32x4){0.f, 0.f, 0.f, 0.f};

    for (int kk = 0; kk < 8; ++kk) {
      const int k0 = kk * 64;
      {  // stage A: x 128 tok x 64 k (fp32 -> bf16), 16 elems/thread
        int row = t >> 2, q = t & 3;
        const float4* src = reinterpret_cast<const float4*>(
            x + (size_t)(tok0 + row) * 512 + k0 + q * 16);
        float4 f0 = src[0], f1 = src[1], f2 = src[2], f3 = src[3];
        *reinterpret_cast<u16x8*>(&As[row][q * 16])     = cvt8(f0, f1);
        *reinterpret_cast<u16x8*>(&As[row][q * 16 + 8]) = cvt8(f2, f3);
      }
      {  // stage B: [Wk;Wv] 128 o x 64 k (fp32 -> bf16)
        int row = t >> 2, q = t & 3;
        const float* wsrc = (row < 64) ? (Wk + (size_t)row * 512)
                                       : (Wv + (size_t)(row - 64) * 512);
        const float4* src = reinterpret_cast<const float4*>(wsrc + k0 + q * 16);
        float4 f0 = src[0], f1 = src[1], f2 = src[2], f3 = src[3];
        *reinterpret_cast<u16x8*>(&Bs[row][q * 16])     = cvt8(f0, f1);
        *reinterpret_cast<u16x8*>(&Bs[row][q * 16 + 8]) = cvt8(f2, f3);
      }
      __syncthreads();
#pragma unroll
      for (int s = 0; s < 2; ++s) {
        bf16x8 af[2];
#pragma unroll
        for (int tb = 0; tb < 2; ++tb)
          af[tb] = frag_at(&As[tr * 32 + tb * 16 + lr][s * 32 + lg * 8]);
#pragma unroll
        for (int ob = 0; ob < 4; ++ob) {
          bf16x8 bfr = frag_at(&Bs[oh * 64 + ob * 16 + lr][s * 32 + lg * 8]);
#pragma unroll
          for (int tb = 0; tb < 2; ++tb)
            acc[tb][ob] = mfma16(af[tb], bfr, acc[tb][ob]);
        }
      }
      __syncthreads();
    }
#pragma unroll
    for (int ob = 0; ob < 4; ++ob) {
      const int o = oh * 64 + ob * 16 + lr;
      const float bias = (o < 64) ? bk[o] : bv[o - 64];
#pragma unroll
      for (int tb = 0; tb < 2; ++tb)
#pragma unroll
        for (int i = 0; i < 4; ++i) {
          const int token = tok0 + tr * 32 + tb * 16 + lg * 4 + i;
          const unsigned short hv = f2bf(acc[tb][ob][i] + bias);
          if (o < 64) kbf[(size_t)token * 64 + o] = hv;
          else        vtbf[(size_t)token * 64 + (o - 64)] = hv;
        }
    }
  } else {
    // ---------------- proj_q: qt[b, o, n] ----------------
    const int bi = blockIdx.x - 128;
    const int b = bi & 7, r = bi >> 3, ot = r >> 4, ntl = r & 15;
    const int o0 = ot * 256, n0 = ntl * 128;
    const int orr = w & 3, nh = w >> 2;  // wave: 64 o x 64 n
    f32x4 acc[4][4];
#pragma unroll
    for (int a = 0; a < 4; ++a)
#pragma unroll
      for (int c = 0; c < 4; ++c) acc[a][c] = (f32x4){0.f, 0.f, 0.f, 0.f};

    for (int kk = 0; kk < 8; ++kk) {
      const int k0 = kk * 64;
      {  // stage A: Wq 256 o x 64 k (fp32 -> bf16), 32 elems/thread
        int row = t >> 1, h = t & 1;
        const float4* src = reinterpret_cast<const float4*>(
            Wq + (size_t)(o0 + row) * 512 + k0 + h * 32);
        float4 f0 = src[0], f1 = src[1];
        *reinterpret_cast<u16x8*>(&As[row][h * 32]) = cvt8(f0, f1);
        float4 f2 = src[2], f3 = src[3];
        *reinterpret_cast<u16x8*>(&As[row][h * 32 + 8]) = cvt8(f2, f3);
        float4 f4 = src[4], f5 = src[5];
        *reinterpret_cast<u16x8*>(&As[row][h * 32 + 16]) = cvt8(f4, f5);
        float4 f6 = src[6], f7 = src[7];
        *reinterpret_cast<u16x8*>(&As[row][h * 32 + 24]) = cvt8(f6, f7);
      }
      {  // stage B: x 128 n x 64 k (fp32 -> bf16)
        int row = t >> 2, q = t & 3;
        const float4* src = reinterpret_cast<const float4*>(
            x + ((size_t)b * 2048 + n0 + row) * 512 + k0 + q * 16);
        float4 f0 = src[0], f1 = src[1], f2 = src[2], f3 = src[3];
        *reinterpret_cast<u16x8*>(&Bs[row][q * 16])     = cvt8(f0, f1);
        *reinterpret_cast<u16x8*>(&Bs[row][q * 16 + 8]) = cvt8(f2, f3);
      }
      __syncthreads();
#pragma unroll
      for (int s = 0; s < 2; ++s) {
        bf16x8 bfr[4];
#pragma unroll
        for (int nb = 0; nb < 4; ++nb)
          bfr[nb] = frag_at(&Bs[nh * 64 + nb * 16 + lr][s * 32 + lg * 8]);
#pragma unroll
        for (int ob = 0; ob < 4; ++ob) {
          bf16x8 af = frag_at(&As[orr * 64 + ob * 16 + lr][s * 32 + lg * 8]);
#pragma unroll
          for (int nb = 0; nb < 4; ++nb)
            acc[ob][nb] = mfma16(af, bfr[nb], acc[ob][nb]);
        }
      }
      __syncthreads();
    }
#pragma unroll
    for (int ob = 0; ob < 4; ++ob)
#pragma unroll
      for (int i = 0; i < 4; ++i) {
        const int o = o0 + orr * 64 + ob * 16 + lg * 4 + i;
        const float bias = bq[o];
#pragma unroll
        for (int nb = 0; nb < 4; ++nb) {
          const int n = n0 + nh * 64 + nb * 16 + lr;
          qt[((size_t)b * 512 + o) * 2048 + n] = f2bf(acc[ob][nb][i] + bias);
        }
      }
  }
}

// ---------------- attention ------------------------------------------------
// Grid 512 = 8 b x 32 mt x 2 ch; 256 threads (4 waves); 2 blocks/CU.
// Block: 64 m rows x 256 c half. Waves partition c (qt read ONCE per block);
// each wave computes S (swapped: mfma(K,vt)) for its own 16 m rows over the
// full 64-n tile -> P lane-local per m=lr -> denominator needs only 2 shfls.
// P shared across waves via double-buffered LDS; ONE barrier per tile.
// k-frags and qt-frags register-double-buffered with one-tile prefetch
// distance (branchless (nt+1)&31).
__global__ __launch_bounds__(256, 2) void attn_kernel(
    const float* __restrict__ x, const unsigned short* __restrict__ kbf,
    const unsigned short* __restrict__ vtbf, const unsigned short* __restrict__ qt,
    const float* __restrict__ g, float* __restrict__ out) {
  __shared__ unsigned short p_lds[2][64][72];  // 18.4 KB
  __shared__ float dsum_lds[64];
  const int t = threadIdx.x;
  const int b = blockIdx.x & 7;           // XCD-local batch
  const int rest = blockIdx.x >> 3;
  const int mt = rest >> 1, ch = rest & 1;
  const int m0 = mt * 64;
  const int w = t >> 6, lane = t & 63, lr = lane & 15, lg = lane >> 4;

  const unsigned short* kbase = kbf + (size_t)b * 2048 * 64;
  // B-frags for S: vt rows of this wave's 16 m rows (m = w*16 + lr)
  const unsigned short* vrow =
      vtbf + (size_t)(b * 2048 + m0 + w * 16 + lr) * 64;
  const bf16x8 qf0 = frag_at(vrow + lg * 8);
  const bf16x8 qf1 = frag_at(vrow + 32 + lg * 8);
  // wave's PV c-range: ch*256 + w*64
  const unsigned short* qtb = qt + ((size_t)b * 512 + ch * 256 + w * 64) * 2048;

  f32x4 acc[4][4];  // [mc][cb]: 64 m x 64 c
#pragma unroll
  for (int mc = 0; mc < 4; ++mc)
#pragma unroll
    for (int cb = 0; cb < 4; ++cb) acc[mc][cb] = (f32x4){0.f, 0.f, 0.f, 0.f};
  float dsum = 0.f;

  // prologue: tile 0 operand prefetch
  bf16x8 kf[4][2], bfr[4][2];
#pragma unroll
  for (int nb = 0; nb < 4; ++nb) {
    const unsigned short* krow = kbase + (size_t)(nb * 16 + lr) * 64;
    kf[nb][0] = frag_at(krow + lg * 8);
    kf[nb][1] = frag_at(krow + 32 + lg * 8);
  }
#pragma unroll
  for (int cb = 0; cb < 4; ++cb) {
    const unsigned short* qrow = qtb + (size_t)(cb * 16 + lr) * 2048;
    bfr[cb][0] = frag_at(qrow + lg * 8);
    bfr[cb][1] = frag_at(qrow + 32 + lg * 8);
  }

  for (int nt = 0; nt < 32; ++nt) {
    const int buf = nt & 1;
    const int nn = ((nt + 1) & 31) * 64;  // next tile (wraps; branchless)

    // S (swapped): lane holds P[m = w*16+lr][n = nb*16 + lg*4 + i]
    f32x4 sacc[4];
#pragma unroll
    for (int nb = 0; nb < 4; ++nb) {
      sacc[nb] = (f32x4){0.f, 0.f, 0.f, 0.f};
      sacc[nb] = mfma16(kf[nb][0], qf0, sacc[nb]);
      sacc[nb] = mfma16(kf[nb][1], qf1, sacc[nb]);
    }
    // prefetch k-frags for next tile (cover: exp+barrier+PV)
#pragma unroll
    for (int nb = 0; nb < 4; ++nb) {
      const unsigned short* krow = kbase + (size_t)(nn + nb * 16 + lr) * 64;
      kf[nb][0] = frag_at(krow + lg * 8);
      kf[nb][1] = frag_at(krow + 32 + lg * 8);
    }
    // exp + lane-local denominator + pack + LDS write ([m][n] A-layout)
#pragma unroll
    for (int nb = 0; nb < 4; ++nb) {
      float e0 = __expf(sacc[nb][0]);
      float e1 = __expf(sacc[nb][1]);
      float e2 = __expf(sacc[nb][2]);
      float e3 = __expf(sacc[nb][3]);
      dsum += (e0 + e1) + (e2 + e3);
      uint2 pk;
      pk.x = pack2bf(e0, e1);
      pk.y = pack2bf(e2, e3);
      *reinterpret_cast<uint2*>(&p_lds[buf][w * 16 + lr][nb * 16 + lg * 4]) = pk;
    }
    __syncthreads();  // the only barrier per tile

    // PV: acc[64m x 64c] += P . qt
#pragma unroll
    for (int mc = 0; mc < 4; ++mc) {
      bf16x8 pf0 = frag_at(&p_lds[buf][mc * 16 + lr][lg * 8]);
      bf16x8 pf1 = frag_at(&p_lds[buf][mc * 16 + lr][32 + lg * 8]);
#pragma unroll
      for (int cb = 0; cb < 4; ++cb) {
        acc[mc][cb] = mfma16(pf0, bfr[cb][0], acc[mc][cb]);
        acc[mc][cb] = mfma16(pf1, bfr[cb][1], acc[mc][cb]);
      }
    }
    // prefetch qt-frags for next tile (cover: next S+exp+barrier)
#pragma unroll
    for (int cb = 0; cb < 4; ++cb) {
      const unsigned short* qrow = qtb + (size_t)(cb * 16 + lr) * 2048 + nn;
      bfr[cb][0] = frag_at(qrow + lg * 8);
      bfr[cb][1] = frag_at(qrow + 32 + lg * 8);
    }
  }

  // denominator: lane holds partial for m = w*16+lr; combine lg groups
  dsum += __shfl_xor(dsum, 16);
  dsum += __shfl_xor(dsum, 32);
  if (lane < 16) dsum_lds[w * 16 + lane] = dsum;
  __syncthreads();

  const float gamma = g[0];
#pragma unroll
  for (int mc = 0; mc < 4; ++mc) {
#pragma unroll
    for (int i = 0; i < 4; ++i) {
      const int mrow = mc * 16 + lg * 4 + i;
      const float s = gamma / dsum_lds[mrow];
      const size_t base =
          ((size_t)b * 2048 + m0 + mrow) * 512 + ch * 256 + w * 64;
#pragma unroll
      for (int cb = 0; cb < 4; ++cb) {
        const size_t idx = base + cb * 16 + lr;
        out[idx] = acc[mc][cb][i] * s + x[idx];
      }
    }
  }
}

// ---------------- launcher ----------------
extern "C" void kernel_launch(void* const* d_in, const int* in_sizes, int n_in,
                              void* d_out, int out_size, void* d_ws, size_t ws_size,
                              hipStream_t stream) {
  const float* x  = (const float*)d_in[0];
  const float* Wk = (const float*)d_in[1];
  const float* bk = (const float*)d_in[2];
  const float* Wv = (const float*)d_in[3];
  const float* bv = (const float*)d_in[4];
  const float* Wq = (const float*)d_in[5];
  const float* bq = (const float*)d_in[6];
  const float* g  = (const float*)d_in[7];
  float* out = (float*)d_out;

  char* ws = (char*)d_ws;
  unsigned short* kbf  = (unsigned short*)(ws);               // 2 MB
  unsigned short* vtbf = (unsigned short*)(ws + 2097152);     // 2 MB
  unsigned short* qt   = (unsigned short*)(ws + 4194304);     // 16 MB

  hipLaunchKernelGGL(proj_all_kernel, dim3(384), dim3(512), 0, stream,
                     x, Wk, bk, Wv, bv, Wq, bq, kbf, vtbf, qt);
  hipLaunchKernelGGL(attn_kernel, dim3(512), dim3(256), 0, stream,
                     x, kbf, vtbf, qt, g, out);
}